// Round 6
// baseline (139.014 us; speedup 1.0000x reference)
//
#include <hip/hip_runtime.h>
#include <math.h>

#define CD  128
#define HFD 32
#define WFD 88

typedef __attribute__((ext_vector_type(4))) float  f4;
typedef __attribute__((ext_vector_type(8))) __bf16 b8;

__device__ __forceinline__ f4 mfma16(b8 a, b8 b, f4 c) {
  return __builtin_amdgcn_mfma_f32_16x16x32_bf16(a, b, c, 0, 0, 0);
}

// ---------------------------------------------------------------------------
// Kernel 1: invert B 4x4 lidar-aug matrices (double-precision Gauss-Jordan)
// ---------------------------------------------------------------------------
__global__ void prep_inv_kernel(const float* __restrict__ aug,
                                float* __restrict__ auginv, int B) {
  int b = threadIdx.x;
  if (b >= B) return;
  double m[4][8];
  for (int i = 0; i < 4; ++i)
    for (int j = 0; j < 4; ++j) {
      m[i][j]     = (double)aug[b * 16 + i * 4 + j];
      m[i][4 + j] = (i == j) ? 1.0 : 0.0;
    }
  for (int col = 0; col < 4; ++col) {
    int piv = col;
    double best = fabs(m[col][col]);
    for (int r = col + 1; r < 4; ++r) {
      double v = fabs(m[r][col]);
      if (v > best) { best = v; piv = r; }
    }
    if (piv != col)
      for (int j = 0; j < 8; ++j) {
        double t = m[col][j]; m[col][j] = m[piv][j]; m[piv][j] = t;
      }
    double f = 1.0 / m[col][col];
    for (int j = 0; j < 8; ++j) m[col][j] *= f;
    for (int r = 0; r < 4; ++r)
      if (r != col) {
        double gg = m[r][col];
        for (int j = 0; j < 8; ++j) m[r][j] -= gg * m[col][j];
      }
  }
  for (int i = 0; i < 4; ++i)
    for (int j = 0; j < 4; ++j)
      auginv[b * 16 + i * 4 + j] = (float)m[i][4 + j];
}

// ---------------------------------------------------------------------------
// Kernel 2: transpose img_feats (B,C,H,W) -> (B,H,W,C) in bf16
// ---------------------------------------------------------------------------
__global__ void transpose_img_kernel(const float* __restrict__ img,
                                     __bf16* __restrict__ imgT, int total) {
  int o = blockIdx.x * blockDim.x + threadIdx.x;
  if (o >= total) return;
  int c   = o & (CD - 1);
  int pos = o >> 7;          // (b*HF + y)*WF + x
  int xw  = pos % WFD;
  int tmp = pos / WFD;       // b*HF + y
  int yh  = tmp & (HFD - 1);
  int b   = tmp >> 5;
  imgT[o] = (__bf16)img[((b * CD + c) * HFD + yh) * WFD + xw];
}

// ---------------------------------------------------------------------------
// Kernel 3: pack weights into bf16 A-fragment register order.
// Fragment f occupies shorts [f*512, (f+1)*512): lane l holds 8 shorts at
// f*512 + l*8. W1t = frags 0..15, We1t = frags 16..79, We2t = frags 80..111.
// W1t/We1t (cat-side) use k = 32*kb + 8*(lane>>4) + j (contig-8 map).
// We2t (h-side) keeps   k = 32*kb + 4*(lane>>4) + (j&3) + 16*(j>>2)
// (pinned by the in-register acc2->b3 repack).
// ---------------------------------------------------------------------------
__global__ void pack_weights_kernel(const float* __restrict__ W1,
                                    const float* __restrict__ We1,
                                    const float* __restrict__ We2,
                                    short* __restrict__ W1t,
                                    short* __restrict__ We1t,
                                    short* __restrict__ We2t) {
  int i = blockIdx.x * 256 + threadIdx.x;
  const float* W; short* O; int KB, Nw, idx; bool cmap;
  if (i < 8192)       { W = W1;  O = W1t;  KB = 4; Nw = 64;  idx = i;         cmap = true;  }
  else if (i < 40960) { W = We1; O = We1t; KB = 8; Nw = 128; idx = i - 8192;  cmap = true;  }
  else if (i < 57344) { W = We2; O = We2t; KB = 4; Nw = 128; idx = i - 40960; cmap = false; }
  else return;
  const int j    = idx & 7;
  const int lane = (idx >> 3) & 63;
  const int blk  = idx >> 9;
  const int kb   = blk % KB, mb = blk / KB;
  const int ch   = 16 * mb + (lane & 15);
  const int k    = cmap ? (32 * kb + 8 * (lane >> 4) + j)
                        : (32 * kb + 4 * (lane >> 4) + (j & 3) + 16 * (j >> 2));
  __bf16 h = (__bf16)W[k * Nw + ch];
  short s;
  __builtin_memcpy(&s, &h, 2);
  O[idx] = s;
}

// ---------------------------------------------------------------------------
// Per-point geometry + cat^T fragment build (lane g owns k-slice 8g..8g+7
// of each 32-block).
// ---------------------------------------------------------------------------
__device__ __forceinline__ void geo_cat(
    int nc, int g, const float* __restrict__ x,
    const int* __restrict__ indices, const __bf16* __restrict__ imgT,
    const float* __restrict__ auginv, const float* __restrict__ trans,
    float vsx, float vsy, float vsz, float pcx, float pcy, float pcz,
    float su, float sv, b8* catf, float& vf_o, float& rn_o) {
  const int4 idx = *reinterpret_cast<const int4*>(indices + (size_t)nc * 4);
  const int  b   = idx.x;
  const float cx = (float)idx.w * vsx + pcx + 0.5f * vsx;
  const float cy = (float)idx.z * vsy + pcy + 0.5f * vsy;
  const float cz = (float)idx.y * vsz + pcz + 0.5f * vsz;

  const f4 A0 = *reinterpret_cast<const f4*>(auginv + b * 16 + 0);
  const f4 A1 = *reinterpret_cast<const f4*>(auginv + b * 16 + 4);
  const f4 A2 = *reinterpret_cast<const f4*>(auginv + b * 16 + 8);
  const f4 A3 = *reinterpret_cast<const f4*>(auginv + b * 16 + 12);
  const float h0 = A0[0] * cx + A0[1] * cy + A0[2] * cz + A0[3];
  const float h1 = A1[0] * cx + A1[1] * cy + A1[2] * cz + A1[3];
  const float h2 = A2[0] * cx + A2[1] * cy + A2[2] * cz + A2[3];
  const float h3 = A3[0] * cx + A3[1] * cy + A3[2] * cz + A3[3];
  const f4 T0 = *reinterpret_cast<const f4*>(trans + b * 12 + 0);
  const f4 T1 = *reinterpret_cast<const f4*>(trans + b * 12 + 4);
  const f4 T2 = *reinterpret_cast<const f4*>(trans + b * 12 + 8);
  const float q0    = T0[0] * h0 + T0[1] * h1 + T0[2] * h2 + T0[3] * h3;
  const float q1    = T1[0] * h0 + T1[1] * h1 + T1[2] * h2 + T1[3] * h3;
  const float depth = T2[0] * h0 + T2[1] * h1 + T2[2] * h2 + T2[3] * h3;
  const float safe  = fmaxf(depth, 1e-5f);
  const float u = q0 / safe, v = q1 / safe;
  const float un = 2.0f * (u * su) / 87.0f - 1.0f;
  const float vn = 2.0f * (v * sv) / 31.0f - 1.0f;
  vf_o = (depth > 1e-5f && fabsf(un) <= 1.0f && fabsf(vn) <= 1.0f) ? 1.0f : 0.0f;
  float rn = sqrtf(cx * cx + cy * cy) / 54.0f;
  rn_o = fminf(fmaxf(rn, 0.0f), 1.0f);

  const float xp  = (un + 1.0f) * 0.5f * 87.0f;
  const float yp  = (vn + 1.0f) * 0.5f * 31.0f;
  const float x0f = floorf(xp), y0f = floorf(yp);
  const float wx1 = xp - x0f, wy1 = yp - y0f;
  const float wx0 = 1.0f - wx1, wy0 = 1.0f - wy1;
  const bool okx0 = (x0f >= 0.0f) && (x0f <= 87.0f);
  const bool okx1 = (x0f + 1.0f >= 0.0f) && (x0f + 1.0f <= 87.0f);
  const bool oky0 = (y0f >= 0.0f) && (y0f <= 31.0f);
  const bool oky1 = (y0f + 1.0f >= 0.0f) && (y0f + 1.0f <= 31.0f);
  const int ix0 = (int)fminf(fmaxf(x0f, 0.0f), 87.0f);
  const int ix1 = (int)fminf(fmaxf(x0f + 1.0f, 0.0f), 87.0f);
  const int iy0 = (int)fminf(fmaxf(y0f, 0.0f), 31.0f);
  const int iy1 = (int)fminf(fmaxf(y0f + 1.0f, 0.0f), 31.0f);
  const float w00 = (okx0 && oky0) ? (wx0 * wy0) : 0.0f;
  const float w01 = (okx1 && oky0) ? (wx1 * wy0) : 0.0f;
  const float w10 = (okx0 && oky1) ? (wx0 * wy1) : 0.0f;
  const float w11 = (okx1 && oky1) ? (wx1 * wy1) : 0.0f;
  const int o00 = (iy0 * WFD + ix0) * CD;
  const int o01 = (iy0 * WFD + ix1) * CD;
  const int o10 = (iy1 * WFD + ix0) * CD;
  const int o11 = (iy1 * WFD + ix1) * CD;
  const __bf16* ib = imgT + (size_t)b * (HFD * WFD * CD);

  // x half: k = 32kb + 8g + j  -> lane loads 8 contiguous floats
  const float* xr = x + (size_t)nc * CD + 8 * g;
#pragma unroll
  for (int kb = 0; kb < 4; ++kb) {
    const f4 a = *reinterpret_cast<const f4*>(xr + 32 * kb);
    const f4 c = *reinterpret_cast<const f4*>(xr + 32 * kb + 4);
    b8 t;
#pragma unroll
    for (int e = 0; e < 4; ++e) {
      t[e]     = (__bf16)a[e];
      t[4 + e] = (__bf16)c[e];
    }
    catf[kb] = t;
  }
  // sampled half: one 16-B bf16 load per corner per kb
#pragma unroll
  for (int kb = 0; kb < 4; ++kb) {
    const int off = 32 * kb + 8 * g;
    const b8 f00 = *reinterpret_cast<const b8*>(ib + o00 + off);
    const b8 f01 = *reinterpret_cast<const b8*>(ib + o01 + off);
    const b8 f10 = *reinterpret_cast<const b8*>(ib + o10 + off);
    const b8 f11 = *reinterpret_cast<const b8*>(ib + o11 + off);
    b8 t;
#pragma unroll
    for (int e = 0; e < 8; ++e) {
      const float s = w00 * (float)f00[e] + w01 * (float)f01[e] +
                      w10 * (float)f10[e] + w11 * (float)f11[e];
      t[e] = (__bf16)s;
    }
    catf[4 + kb] = t;
  }
}

// ---------------------------------------------------------------------------
// Per-point epilogue: mask, norms, LN; x reloaded (L2-hot).
// ---------------------------------------------------------------------------
__device__ __forceinline__ void epilogue_pt(
    const f4* acc3, float vf, float rn, float sfg, int n, int nc, int g, int N,
    const float* __restrict__ x, const float* __restrict__ lng,
    const float* __restrict__ lnb, const float* __restrict__ b2,
    float* __restrict__ out, size_t OFF_PFG, size_t OFF_GAIN, size_t OFF_RN,
    size_t OFF_VAL) {
  f4 xrv[8];
  float sd = 0.0f, sx2 = 0.0f, sr = 0.0f, sr2 = 0.0f;
#pragma unroll
  for (int mb = 0; mb < 8; ++mb) {
    const f4 xv = *reinterpret_cast<const f4*>(x + (size_t)nc * CD + 16 * mb + 4 * g);
    const f4 d  = acc3[mb] * vf;
    const f4 r  = xv + d;
    xrv[mb] = r;
#pragma unroll
    for (int e = 0; e < 4; ++e) {
      sd  += d[e] * d[e];
      sx2 += xv[e] * xv[e];
      sr  += r[e];
      sr2 += r[e] * r[e];
    }
  }
  sd  += __shfl_xor(sd, 16);  sd  += __shfl_xor(sd, 32);
  sx2 += __shfl_xor(sx2, 16); sx2 += __shfl_xor(sx2, 32);
  sr  += __shfl_xor(sr, 16);  sr  += __shfl_xor(sr, 32);
  sr2 += __shfl_xor(sr2, 16); sr2 += __shfl_xor(sr2, 32);

  const float mu   = sr * (1.0f / 128.0f);
  const float var  = sr2 * (1.0f / 128.0f) - mu * mu;
  const float rstd = rsqrtf(var + 1e-5f);
  const float gn   = sqrtf(sd) / (sqrtf(sx2) + 1e-6f);
  const float fgain = fminf(fmaxf(1.0f - expf(-gn), 0.0f), 1.0f);

  if (n < N) {
#pragma unroll
    for (int mb = 0; mb < 8; ++mb) {
      const f4 gm = *reinterpret_cast<const f4*>(lng + 16 * mb + 4 * g);
      const f4 bt = *reinterpret_cast<const f4*>(lnb + 16 * mb + 4 * g);
      const f4 o  = (xrv[mb] - mu) * rstd * gm + bt;
      *reinterpret_cast<f4*>(out + (size_t)n * CD + 16 * mb + 4 * g) = o;
    }
    if (g == 0) {
      out[OFF_PFG  + n] = 1.0f / (1.0f + expf(-(sfg + b2[0])));
      out[OFF_GAIN + n] = fgain;
      out[OFF_RN   + n] = rn;
      out[OFF_VAL  + n] = vf;
    }
  }
}

// ---------------------------------------------------------------------------
// Main fused kernel: 768 threads = 12 waves; 32 points/wave (2 point-groups,
// 384 pts/block). Weights async-staged to LDS via global_load_lds (width 16);
// every LDS fragment read feeds 2 MFMAs.
// ---------------------------------------------------------------------------
__global__ __launch_bounds__(768)
void fused_mfma_kernel(const float* __restrict__ x,
                       const int* __restrict__ indices,
                       const float* __restrict__ voxel_size,
                       const float* __restrict__ pc_range,
                       const float* __restrict__ trans,
                       const float* __restrict__ auginv,
                       const __bf16* __restrict__ imgT,
                       const short* __restrict__ wsrc,   // W1t|We1t|We2t packed
                       const float* __restrict__ b1,
                       const float* __restrict__ W2,
                       const float* __restrict__ b2,
                       const float* __restrict__ be1,
                       const float* __restrict__ be2,
                       const float* __restrict__ lng,
                       const float* __restrict__ lnb,
                       const int* __restrict__ img_h_p,
                       const int* __restrict__ img_w_p,
                       float* __restrict__ out, int N) {
  __shared__ __align__(16) short wlds[57344];   // 112 KB: 112 fragments
  const int tid  = threadIdx.x;
  const int lane = tid & 63;
  const int wv   = tid >> 6;        // 0..11
  const int g    = lane >> 4;
  const int pl   = lane & 15;
  const int n0   = blockIdx.x * 384 + wv * 32 + pl;
  const int n1   = n0 + 16;
  const int nc0  = (n0 < N) ? n0 : (N - 1);
  const int nc1  = (n1 < N) ? n1 : (N - 1);

  const size_t NN       = (size_t)N;
  const size_t OFF_PFG  = NN * CD;
  const size_t OFF_GAIN = OFF_PFG + NN;
  const size_t OFF_RN   = OFF_GAIN + NN;
  const size_t OFF_VAL  = OFF_RN + NN;

  // ---- async staging: wave wv stages fragments {wv, wv+12, ...} ----
  // Fragment f: lane l's 16 B at wsrc + f*512 + l*8 -> LDS wlds + f*512 + l*8
  // (global_load_lds dest = wave-uniform base + lane*16, exactly our layout)
#pragma unroll
  for (int i = 0; i < 10; ++i) {
    const int f = wv + i * 12;
    if (f < 112) {
      __builtin_amdgcn_global_load_lds(
          (const __attribute__((address_space(1))) unsigned int*)
              (wsrc + (size_t)f * 512 + lane * 8),
          (__attribute__((address_space(3))) unsigned int*)(wlds + f * 512),
          16, 0, 0);
    }
  }

  const float vsx = voxel_size[0] * 8.0f;
  const float vsy = voxel_size[1] * 8.0f;
  const float vsz = voxel_size[2] * 8.0f;
  const float pcx = pc_range[0], pcy = pc_range[1], pcz = pc_range[2];
  const float su  = (float)WFD / (float)(*img_w_p);
  const float sv  = (float)HFD / (float)(*img_h_p);

  // ---- geometry + cat fragments for both point-groups (overlaps staging) ----
  b8 cat0[8], cat1[8];
  float vf0, rn0, vf1, rn1;
  geo_cat(nc0, g, x, indices, imgT, auginv, trans, vsx, vsy, vsz,
          pcx, pcy, pcz, su, sv, cat0, vf0, rn0);
  geo_cat(nc1, g, x, indices, imgT, auginv, trans, vsx, vsy, vsz,
          pcx, pcy, pcz, su, sv, cat1, vf1, rn1);

  __syncthreads();   // drains global_load_lds (vmcnt) + makes weights visible

  const short* wb = wlds + lane * 8;   // lane-local base; frag f at +f*512

  // ---- fg MLP: frags 0..15, dual point-group ----
  float sfg0 = 0.0f, sfg1 = 0.0f;
#pragma unroll
  for (int mb = 0; mb < 4; ++mb) {
    const f4 bi = *reinterpret_cast<const f4*>(b1 + 16 * mb + 4 * g);
    f4 a0 = bi, a1 = bi;
#pragma unroll
    for (int kb = 0; kb < 4; ++kb) {
      const b8 w = *reinterpret_cast<const b8*>(wb + (mb * 4 + kb) * 512);
      a0 = mfma16(w, cat0[kb], a0);
      a1 = mfma16(w, cat1[kb], a1);
    }
    const f4 w2v = *reinterpret_cast<const f4*>(W2 + 16 * mb + 4 * g);
#pragma unroll
    for (int e = 0; e < 4; ++e) {
      sfg0 += fmaxf(a0[e], 0.0f) * w2v[e];
      sfg1 += fmaxf(a1[e], 0.0f) * w2v[e];
    }
  }
  sfg0 += __shfl_xor(sfg0, 16); sfg0 += __shfl_xor(sfg0, 32);
  sfg1 += __shfl_xor(sfg1, 16); sfg1 += __shfl_xor(sfg1, 32);

  // ---- GEMM2 in mb-pairs (frags 16..79); pair packs to b3[pr], dual pg ----
  b8 b30[4], b31[4];
#pragma unroll
  for (int pr = 0; pr < 4; ++pr) {
    const f4 biA = *reinterpret_cast<const f4*>(be1 + 16 * (2 * pr) + 4 * g);
    const f4 biB = *reinterpret_cast<const f4*>(be1 + 16 * (2 * pr + 1) + 4 * g);
    f4 aA0 = biA, aB0 = biB, aA1 = biA, aB1 = biB;
#pragma unroll
    for (int kb = 0; kb < 8; ++kb) {
      const b8 wA = *reinterpret_cast<const b8*>(wb + (16 + (2 * pr) * 8 + kb) * 512);
      const b8 wB = *reinterpret_cast<const b8*>(wb + (16 + (2 * pr + 1) * 8 + kb) * 512);
      aA0 = mfma16(wA, cat0[kb], aA0);
      aB0 = mfma16(wB, cat0[kb], aB0);
      aA1 = mfma16(wA, cat1[kb], aA1);
      aB1 = mfma16(wB, cat1[kb], aB1);
    }
    b8 t0, t1;
#pragma unroll
    for (int e = 0; e < 4; ++e) {
      t0[e]     = (__bf16)fmaxf(aA0[e], 0.0f);
      t0[4 + e] = (__bf16)fmaxf(aB0[e], 0.0f);
      t1[e]     = (__bf16)fmaxf(aA1[e], 0.0f);
      t1[4 + e] = (__bf16)fmaxf(aB1[e], 0.0f);
    }
    b30[pr] = t0;
    b31[pr] = t1;
  }

  // ---- GEMM3: delta^T = We2^T * h^T (frags 80..111), dual pg ----
  f4 acc30[8], acc31[8];
#pragma unroll
  for (int mb = 0; mb < 8; ++mb) {
    const f4 bi = *reinterpret_cast<const f4*>(be2 + 16 * mb + 4 * g);
    acc30[mb] = bi;
    acc31[mb] = bi;
  }
#pragma unroll
  for (int kb = 0; kb < 4; ++kb) {
#pragma unroll
    for (int mb = 0; mb < 8; ++mb) {
      const b8 w = *reinterpret_cast<const b8*>(wb + (80 + mb * 4 + kb) * 512);
      acc30[mb] = mfma16(w, b30[kb], acc30[mb]);
      acc31[mb] = mfma16(w, b31[kb], acc31[mb]);
    }
  }

  epilogue_pt(acc30, vf0, rn0, sfg0, n0, nc0, g, N, x, lng, lnb, b2, out,
              OFF_PFG, OFF_GAIN, OFF_RN, OFF_VAL);
  epilogue_pt(acc31, vf1, rn1, sfg1, n1, nc1, g, N, x, lng, lnb, b2, out,
              OFF_PFG, OFF_GAIN, OFF_RN, OFF_VAL);
}

// ---------------------------------------------------------------------------
extern "C" void kernel_launch(void* const* d_in, const int* in_sizes, int n_in,
                              void* d_out, int out_size, void* d_ws, size_t ws_size,
                              hipStream_t stream) {
  const float* x       = (const float*)d_in[0];
  const int*   indices = (const int*)d_in[1];
  const float* voxel   = (const float*)d_in[2];
  const float* pcr     = (const float*)d_in[3];
  const float* aug     = (const float*)d_in[4];
  const float* trans   = (const float*)d_in[5];
  const float* img     = (const float*)d_in[6];
  const float* W1      = (const float*)d_in[7];
  const float* b1      = (const float*)d_in[8];
  const float* W2      = (const float*)d_in[9];
  const float* b2      = (const float*)d_in[10];
  const float* We1     = (const float*)d_in[11];
  const float* be1     = (const float*)d_in[12];
  const float* We2     = (const float*)d_in[13];
  const float* be2     = (const float*)d_in[14];
  const float* lng     = (const float*)d_in[15];
  const float* lnb     = (const float*)d_in[16];
  const int*   img_h   = (const int*)d_in[17];
  const int*   img_w   = (const int*)d_in[18];

  const int N         = in_sizes[0] / CD;
  const int B         = in_sizes[4] / 16;
  const int img_total = in_sizes[6];
  const size_t IMG_BYTES = (size_t)img_total * 2;   // bf16

  char*   wsb    = (char*)d_ws;
  float*  auginv = (float*)wsb;
  __bf16* imgT   = (__bf16*)(wsb + 1024);
  short*  W1t    = (short*)(wsb + 1024 + IMG_BYTES);   // frags 0..15
  short*  We1t   = W1t + 8192;                         // frags 16..79
  short*  We2t   = We1t + 32768;                       // frags 80..111

  prep_inv_kernel<<<1, 64, 0, stream>>>(aug, auginv, B);
  transpose_img_kernel<<<(img_total + 255) / 256, 256, 0, stream>>>(
      img, imgT, img_total);
  pack_weights_kernel<<<224, 256, 0, stream>>>(W1, We1, We2, W1t, We1t, We2t);
  fused_mfma_kernel<<<(N + 383) / 384, 768, 0, stream>>>(
      x, indices, voxel, pcr, trans, auginv, imgT,
      W1t, b1, W2, b2, be1, be2,
      lng, lnb, img_h, img_w, (float*)d_out, N);
}